// Round 1
// baseline (87.240 us; speedup 1.0000x reference)
//
#include <hip/hip_runtime.h>
#include <math.h>

#define BS    32
#define T_    50
#define P_    3
#define TP    150     // T_ * P_
#define HEADS 4
#define NKP   88      // 44 keypoints * 2 coords
#define NFRM  50      // frames; frame 49 is fully masked -> uniform softmax

// One wave (64 lanes) per (b, frame). Rows i = 3f..3f+2 share the same
// unmasked column band [3*flo, 3*fhi+3), so the 9 band kp-rows are loaded
// into registers ONCE and reused for all 3 rows of the frame.
// Frame 49 (rows 147..149) is fully masked -> softmax is uniform 1/TP and
// independent of attn; that block also emits (sum_i idx[b,i])^2 for the
// denominator so the reduce kernel never rescans idx.
//
// partials layout in ws: [0, BS*NFRM) per-frame numerators,
//                        [BS*NFRM, BS*NFRM+BS) per-batch squared idx sums.
__global__ __launch_bounds__(64) void smooth_frames(
    const int*   __restrict__ idx,
    const float* __restrict__ kp,     // (BS, TP, 88)
    const float* __restrict__ attn,   // (BS, H, TP, TP)
    float*       __restrict__ partials)
{
    int bf   = blockIdx.x;
    int b    = bf / NFRM;
    int f    = bf - b * NFRM;
    int lane = threadIdx.x;

    const int*   idxb = idx + b * TP;
    const float* kpb  = kp + (size_t)b * TP * NKP;

    __shared__ __align__(16) float s_kp[3 * NKP];   // used by uniform path only

    if (f == NFRM - 1) {
        // ---------- uniform-softmax path: rows 147..149 ----------
        // per-batch idx sum (for denominator)
        int si = 0;
        for (int k = lane; k < TP; k += 64) si += idxb[k];
        #pragma unroll
        for (int off = 32; off; off >>= 1) si += __shfl_down(si, off);

        // stage the 3 contiguous i-rows (147..149) in LDS
        for (int c = lane; c < 3 * NKP / 4; c += 64)
            ((float4*)s_kp)[c] = ((const float4*)(kpb + (TP - 3) * NKP))[c];
        __syncthreads();

        int id0 = idxb[TP - 3], id1 = idxb[TP - 2], id2 = idxb[TP - 1];

        // one pass over j: each kp row j read once, compared vs all 3 i-rows
        float acc0 = 0.f, acc1 = 0.f, acc2 = 0.f;
        for (int j = lane; j < TP; j += 64) {
            if (idxb[j]) {
                const float4* kj = (const float4*)(kpb + j * NKP);   // 88*4B rows: 16B-aligned
                const float4* p0 = (const float4*)(s_kp);
                const float4* p1 = (const float4*)(s_kp + NKP);
                const float4* p2 = (const float4*)(s_kp + 2 * NKP);
                float s0 = 0.f, s1 = 0.f, s2 = 0.f;
                #pragma unroll
                for (int c = 0; c < NKP / 4; ++c) {
                    float4 q = kj[c];
                    float4 a = p0[c];
                    float4 d = p1[c];
                    float4 e = p2[c];
                    s0 += fabsf(q.x - a.x) + fabsf(q.y - a.y) + fabsf(q.z - a.z) + fabsf(q.w - a.w);
                    s1 += fabsf(q.x - d.x) + fabsf(q.y - d.y) + fabsf(q.z - d.z) + fabsf(q.w - d.w);
                    s2 += fabsf(q.x - e.x) + fabsf(q.y - e.y) + fabsf(q.z - e.z) + fabsf(q.w - e.w);
                }
                acc0 += s0; acc1 += s1; acc2 += s2;
            }
        }
        float acc = (id0 ? acc0 : 0.f) + (id1 ? acc1 : 0.f) + (id2 ? acc2 : 0.f);
        #pragma unroll
        for (int off = 32; off; off >>= 1) acc += __shfl_down(acc, off);

        if (lane == 0) {
            partials[bf] = acc * ((float)HEADS / (float)TP);
            float fs = (float)si;
            partials[BS * NFRM + b] = fs * fs;
        }
        return;
    }

    // ---------- band-softmax path: rows i0..i0+2, band cols [jlo, jlo+nj) ----------
    int i0  = P_ * f;
    int id0 = idxb[i0], id1 = idxb[i0 + 1], id2 = idxb[i0 + 2];
    if (!(id0 | id1 | id2)) {            // all 3 rows contribute exactly 0
        if (lane == 0) partials[bf] = 0.f;   // ws is poisoned -> must write
        return;
    }

    int flo = f > 0 ? f - 1 : 0;
    int fhi = f < T_ - 2 ? f + 1 : T_ - 2;
    int jlo = flo * P_;
    int nj  = (fhi - flo + 1) * P_;      // 6 (edge frames) or 9

    // preload the (<=9) band kp-rows into registers, component-per-lane:
    // lane holds components {lane, lane+64}
    bool hi = lane < NKP - 64;           // lanes 0..23 carry components 64..87
    float kj0[9], kj1[9];
    #pragma unroll
    for (int jj = 0; jj < 9; ++jj) {
        int j = jlo + (jj < nj ? jj : 0);   // clamp keeps loads in-bounds; unused lanes masked later
        kj0[jj] = kpb[j * NKP + lane];
        kj1[jj] = hi ? kpb[j * NKP + 64 + lane] : 0.f;
    }

    // softmax lane layout: 4 groups of 16 lanes; group = head, lane-in-group = column
    int  h    = lane >> 4;
    int  jx   = lane & 15;
    bool act  = jx < nj;
    float idxj = act ? (float)idxb[jlo + jx] : 0.f;   // same columns for all 3 rows

    float acc = 0.f;                     // per-lane; uniform within each 16-group
    #pragma unroll
    for (int ii = 0; ii < 3; ++ii) {
        int idi = (ii == 0) ? id0 : (ii == 1) ? id1 : id2;
        if (!idi) continue;              // wave-uniform branch
        int i = i0 + ii;

        float a0 = kpb[i * NKP + lane];
        float a1 = hi ? kpb[i * NKP + 64 + lane] : 0.f;

        // L1 distances to all 9 band rows; full 64-lane butterfly so every
        // lane ends with the complete sums (no LDS broadcast needed)
        float d[9];
        #pragma unroll
        for (int jj = 0; jj < 9; ++jj)
            d[jj] = fabsf(kj0[jj] - a0) + fabsf(kj1[jj] - a1);
        #pragma unroll
        for (int jj = 0; jj < 9; ++jj) {
            #pragma unroll
            for (int off = 32; off; off >>= 1) d[jj] += __shfl_xor(d[jj], off);
        }
        // lw = d[jx] via compile-time select chain (no runtime reg indexing)
        float lw = d[0];
        lw = (jx == 1) ? d[1] : lw;
        lw = (jx == 2) ? d[2] : lw;
        lw = (jx == 3) ? d[3] : lw;
        lw = (jx == 4) ? d[4] : lw;
        lw = (jx == 5) ? d[5] : lw;
        lw = (jx == 6) ? d[6] : lw;
        lw = (jx == 7) ? d[7] : lw;
        lw = (jx == 8) ? d[8] : lw;

        // sparse softmax over the band (masked entries underflow to exact 0
        // in the fp32 reference, so the band sum is exact)
        float a = act ? attn[(((size_t)(b * HEADS + h)) * TP + i) * TP + (jlo + jx)]
                      : -INFINITY;
        float m = a;
        #pragma unroll
        for (int off = 8; off; off >>= 1) m = fmaxf(m, __shfl_xor(m, off));
        float e = act ? expf(a - m) : 0.f;
        float w = e * lw * idxj;         // idxj in {0,1}: exact
        #pragma unroll
        for (int off = 8; off; off >>= 1) { e += __shfl_xor(e, off); w += __shfl_xor(w, off); }
        acc += w / e;                    // per-head weighted mean; e >= 1
    }

    float c0 = __shfl(acc, 0);
    float c1 = __shfl(acc, 16);
    float c2 = __shfl(acc, 32);
    float c3 = __shfl(acc, 48);
    if (lane == 0) partials[bf] = c0 + c1 + c2 + c3;
}

// Reduce 1600 frame partials + 32 precomputed squared batch sums.
// out = num / (1 + H * sum_b (sum_i idx[b,i])^2)
__global__ __launch_bounds__(256) void smooth_reduce(
    const float* __restrict__ partials,
    float*       __restrict__ out)
{
    int tid = threadIdx.x;

    float s = 0.f;
    for (int k = tid; k < BS * NFRM; k += 256) s += partials[k];
    float q = (tid < BS) ? partials[BS * NFRM + tid] : 0.f;   // all in wave 0

    #pragma unroll
    for (int off = 32; off; off >>= 1) {
        s += __shfl_down(s, off);
        q += __shfl_down(q, off);
    }
    __shared__ float s_red[4], s_q[4];
    if ((tid & 63) == 0) { s_red[tid >> 6] = s; s_q[tid >> 6] = q; }
    __syncthreads();

    if (tid == 0) {
        float num = s_red[0] + s_red[1] + s_red[2] + s_red[3];
        float tot = s_q[0] + s_q[1] + s_q[2] + s_q[3];
        out[0] = num / (1.0f + (float)HEADS * tot);
    }
}

extern "C" void kernel_launch(void* const* d_in, const int* in_sizes, int n_in,
                              void* d_out, int out_size, void* d_ws, size_t ws_size,
                              hipStream_t stream)
{
    const int*   idx  = (const int*)  d_in[0];
    // d_in[1] = idx_mask (unused), d_in[2] = idx_kp (unused)
    const float* kp   = (const float*)d_in[3];
    const float* attn = (const float*)d_in[4];
    float* out      = (float*)d_out;
    float* partials = (float*)d_ws;   // BS*NFRM + BS floats

    smooth_frames<<<BS * NFRM, 64, 0, stream>>>(idx, kp, attn, partials);
    smooth_reduce<<<1, 256, 0, stream>>>(partials, out);
}